// Round 11
// baseline (376.126 us; speedup 1.0000x reference)
//
#include <hip/hip_runtime.h>

// ---------------- types / helpers ----------------
typedef __attribute__((ext_vector_type(8))) short short8v;   // 8 bf16 (4 VGPR)
typedef __attribute__((ext_vector_type(4))) float float4v;   // MFMA acc
typedef unsigned short ushortT;

__device__ __forceinline__ unsigned short f2bf(float f) {
  union { float f; unsigned u; } a; a.f = f;
  unsigned r = a.u + 0x7fffu + ((a.u >> 16) & 1u);   // RNE
  return (unsigned short)(r >> 16);
}
__device__ __forceinline__ float2 up2(unsigned u) {  // packed 2xbf16 -> 2 floats
  union { unsigned u; float f; } a, b;
  a.u = u << 16; b.u = u & 0xffff0000u;
  return make_float2(a.f, b.f);
}
__device__ __forceinline__ void gl_lds16(const void* g, void* l) {
  __builtin_amdgcn_global_load_lds(
      (const __attribute__((address_space(1))) void*)g,
      (__attribute__((address_space(3))) void*)l, 16, 0, 0);
}

#define MFMA16(d, a, b) d = __builtin_amdgcn_mfma_f32_16x16x32_bf16(a, b, d, 0, 0, 0)

// ---------------- K0: fused prep — weight converts + groupnorm stats -------
__global__ __launch_bounds__(256) void prep(const float* __restrict__ qkvw,
                                            const float* __restrict__ pw,
                                            const float* __restrict__ x,
                                            ushortT* __restrict__ wq_b,
                                            ushortT* __restrict__ wp_b,
                                            float2* __restrict__ stats) {
  int bid = blockIdx.x, tid = threadIdx.x;
  if (bid < 1024) {
    const float* src = (bid < 768) ? qkvw : pw;
    ushortT* dst     = (bid < 768) ? wq_b : wp_b;
    int base = (bid < 768) ? bid : (bid - 768);
    int i = (base * 256 + tid) * 4;
    float4 v = *(const float4*)(src + i);
    uint2 o;
    o.x = (unsigned)f2bf(v.x) | ((unsigned)f2bf(v.y) << 16);
    o.y = (unsigned)f2bf(v.z) | ((unsigned)f2bf(v.w) << 16);
    *(uint2*)(dst + i) = o;
    return;
  }
  int bg = bid - 1024;
  const float* base = x + (size_t)bg * 65536;
  float s = 0.f, s2 = 0.f;
  for (int i = tid; i < 16384; i += 256) {
    float4 v = *(const float4*)(base + (size_t)i * 4);
    s  += v.x + v.y + v.z + v.w;
    s2 += v.x * v.x + v.y * v.y + v.z * v.z + v.w * v.w;
  }
  #pragma unroll
  for (int off = 32; off > 0; off >>= 1) {
    s  += __shfl_down(s, off);
    s2 += __shfl_down(s2, off);
  }
  __shared__ float red[8];
  int w = tid >> 6, l = tid & 63;
  if (l == 0) { red[w] = s; red[w + 4] = s2; }
  __syncthreads();
  if (tid == 0) {
    float ts = red[0] + red[1] + red[2] + red[3];
    float t2 = red[4] + red[5] + red[6] + red[7];
    float mean = ts * (1.f / 65536.f);
    float var  = t2 * (1.f / 65536.f) - mean * mean;
    stats[bg] = make_float2(mean, rsqrtf(var + 1e-5f));
  }
}

// ---------------- K2: normalize + transpose -> h[b*n][c] bf16 ----------------
__global__ __launch_bounds__(512) void norm_tr(const float* __restrict__ x,
                                               const float* __restrict__ nw,
                                               const float* __restrict__ nb,
                                               const float2* __restrict__ stats,
                                               ushortT* __restrict__ h) {
  __shared__ float t[64][65];
  int n0 = blockIdx.x * 64, c0 = blockIdx.y * 64, b = blockIdx.z;
  int tx = threadIdx.x, ty = threadIdx.y;
  #pragma unroll
  for (int j = ty; j < 64; j += 8) {
    int c = c0 + j;
    float2 ms = stats[b * 32 + (c >> 4)];
    float v = x[((size_t)b * 512 + c) * 4096 + n0 + tx];
    t[j][tx] = (v - ms.x) * ms.y * nw[c] + nb[c];
  }
  __syncthreads();
  #pragma unroll
  for (int j = ty; j < 64; j += 8) {
    int n = n0 + j;
    h[((size_t)b * 4096 + n) * 512 + c0 + tx] = f2bf(t[tx][j]);
  }
}

// ================= m97-style 128x128 GEMM core =============================
// 256 thr / 4 waves (2x2, 64x64 quadrants), BK=32, 16 KB single-buffered LDS,
// 2-barrier K-loop (stage -> sync(vmcnt0) -> read+MFMA -> sync). acc[4][4] =
// 64 AGPR + ~110 VGPR -> 2 blocks/CU resident: the other block's compute
// hides this block's staging + epilogue (the 256^2 structure's 1-block/CU
// serialization was the 131us plateau). LDS swizzle: 16B slot ^= (row>>1)&3,
// applied BOTH sides (pre-swizzled global src for gl_lds, swizzled ds_read).
__device__ __forceinline__ void core128(const ushortT* __restrict__ A,
                                        const ushortT* __restrict__ Bm,
                                        ushortT* lds, int m0, int n0,
                                        float4v (&acc)[4][4]) {
  char* ldsb = (char*)lds;
  const int tid = threadIdx.x;
  const int w = tid >> 6, l = tid & 63;
  const int wm = w >> 1, wn = w & 1;

  // staging: thread covers 16B chunks tid and 256+tid of each 8 KB region
  const int r0 = tid >> 2, r1 = (256 + tid) >> 2;       // rows 0..63, 64..127
  const int s0 = (tid & 3) ^ ((r0 >> 1) & 3);
  const int s1 = (tid & 3) ^ ((r1 >> 1) & 3);
  const size_t gA0 = (size_t)r0 * 512 + s0 * 8;         // element offsets
  const size_t gA1 = (size_t)r1 * 512 + s1 * 8;
  const int d0 = tid * 16, d1 = (256 + tid) * 16;       // linear LDS dest

  // fragment reads: row R = q*64 + i*16 + (l&15); swizzle term invariant
  // across i (16>>1 = 8 === 0 mod 4) and quadrant (64>>1 = 32 === 0 mod 4)
  const int cs = ((l >> 4) ^ (((l & 15) >> 1) & 3)) * 16;
  const int ab = wm * 4096 + (l & 15) * 64 + cs;
  const int bb = 8192 + wn * 4096 + (l & 15) * 64 + cs;

  const ushortT* pa = A + (size_t)m0 * 512;
  const ushortT* pb = Bm + (size_t)n0 * 512;

  #pragma unroll 1
  for (int kt = 0; kt < 16; ++kt) {
    if (kt) __syncthreads();
    gl_lds16(pa + gA0 + kt * 32, ldsb + d0);
    gl_lds16(pa + gA1 + kt * 32, ldsb + d1);
    gl_lds16(pb + gA0 + kt * 32, ldsb + 8192 + d0);
    gl_lds16(pb + gA1 + kt * 32, ldsb + 8192 + d1);
    __syncthreads();                 // drains vmcnt+lgkm before reads
    short8v Af[4], Bf[4];
    #pragma unroll
    for (int i = 0; i < 4; ++i) {
      Af[i] = *(const short8v*)(ldsb + ab + i * 1024);
      Bf[i] = *(const short8v*)(ldsb + bb + i * 1024);
    }
    #pragma unroll
    for (int mi = 0; mi < 4; ++mi)
      #pragma unroll
      for (int ni = 0; ni < 4; ++ni)
        MFMA16(acc[mi][ni], Af[mi], Bf[ni]);
  }
}

// ---------------- K3: qkv GEMM (65536 x 1536 x 512) -> bf16 ----------------
// grid 6144 = 512 m-tiles x 12 n-tiles; XCD-swizzled, n-fastest within XCD
// (A-tile reused 12x in-L2; wq 1.5 MB L2-resident).
__global__ __launch_bounds__(256) void gemm_qkv(const ushortT* __restrict__ h,
                                                const ushortT* __restrict__ wq,
                                                const float* __restrict__ bias,
                                                ushortT* __restrict__ outq) {
  __shared__ ushortT lds[8192];                 // 16 KB
  int bid = blockIdx.x;
  int wg = (bid & 7) * 768 + (bid >> 3);        // bijective (6144 % 8 == 0)
  int m0 = (wg / 12) * 128, n0 = (wg % 12) * 128;
  float4v acc[4][4] = {};
  core128(h, wq, lds, m0, n0, acc);
  const int tid = threadIdx.x;
  const int w = tid >> 6, l = tid & 63;
  const int wm = w >> 1, wn = w & 1;
  __syncthreads();
  ushortT* es = lds + w * 1280;                 // 16 x 72 shorts per wave
  float bb4[4];
  #pragma unroll
  for (int fn = 0; fn < 4; ++fn) bb4[fn] = bias[n0 + wn * 64 + fn * 16 + (l & 15)];
  int r = l >> 2, g = l & 3;
  #pragma unroll
  for (int fm = 0; fm < 4; ++fm) {
    #pragma unroll
    for (int fn = 0; fn < 4; ++fn)
      #pragma unroll
      for (int j = 0; j < 4; ++j)
        es[((l >> 4) * 4 + j) * 72 + fn * 16 + (l & 15)] = f2bf(acc[fm][fn][j] + bb4[fn]);
    // same-wave LDS write->read (compiler inserts lgkmcnt)
    uint4 v0 = *(const uint4*)(es + r * 72 + g * 16);
    uint4 v1 = *(const uint4*)(es + r * 72 + g * 16 + 8);
    size_t mrow = (size_t)m0 + wm * 64 + fm * 16 + r;
    uint4* dst = (uint4*)(outq + mrow * 1536 + n0 + wn * 64 + g * 16);
    dst[0] = v0; dst[1] = v1;
  }
}

// ---------------- K4: attention, LDS-staged & fully coalesced (R10) --------
__global__ __launch_bounds__(256) void attn_k(const ushortT* __restrict__ qkv,
                                              ushortT* __restrict__ o) {
  __shared__ ushortT kv[16 * 1544];            // 49408 B
  const int tid = threadIdx.x;
  const int p0 = blockIdx.x * 16;

  #pragma unroll
  for (int j = 0; j < 12; ++j) {
    int c = j * 256 + tid;
    int row = c / 192, col = c % 192;          // row wave-uniform (64 | 192)
    gl_lds16(qkv + (size_t)(p0 + row) * 1536 + col * 8,
             (char*)kv + row * 3088 + col * 16);
  }
  __syncthreads();

  const int pos = tid >> 4, h = (tid >> 1) & 7, dh = tid & 1;
  const ushortT* rowp = kv + pos * 1544;

  unsigned qv[16];
  {
    const uint4* qs = (const uint4*)(rowp + h * 64 + dh * 32);
    #pragma unroll
    for (int i = 0; i < 4; ++i) {
      uint4 u = qs[i];
      qv[i*4+0] = u.x; qv[i*4+1] = u.y; qv[i*4+2] = u.z; qv[i*4+3] = u.w;
    }
  }
  float lg[8];
  #pragma unroll
  for (int g = 0; g < 8; ++g) {
    const uint4* ks = (const uint4*)(rowp + 512 + g * 64 + dh * 32);
    float s = 0.f;
    #pragma unroll
    for (int i = 0; i < 4; ++i) {
      uint4 u = ks[i];
      float2 k0 = up2(u.x), k1 = up2(u.y), k2 = up2(u.z), k3 = up2(u.w);
      float2 q0 = up2(qv[i*4+0]), q1 = up2(qv[i*4+1]);
      float2 q2 = up2(qv[i*4+2]), q3 = up2(qv[i*4+3]);
      s += q0.x*k0.x + q0.y*k0.y + q1.x*k1.x + q1.y*k1.y
         + q2.x*k2.x + q2.y*k2.y + q3.x*k3.x + q3.y*k3.y;
    }
    s += __shfl_xor(s, 1);                     // combine the two d-halves
    lg[g] = s * 0.125f;
  }
  float mx = lg[0];
  #pragma unroll
  for (int g = 1; g < 8; ++g) mx = fmaxf(mx, lg[g]);
  float ssum = 0.f;
  #pragma unroll
  for (int g = 0; g < 8; ++g) { lg[g] = __expf(lg[g] - mx); ssum += lg[g]; }
  float inv = 1.f / ssum;
  #pragma unroll
  for (int g = 0; g < 8; ++g) lg[g] *= inv;

  float oa[32];
  #pragma unroll
  for (int i = 0; i < 32; ++i) oa[i] = 0.f;
  #pragma unroll
  for (int g = 0; g < 8; ++g) {
    const uint4* vs = (const uint4*)(rowp + 1024 + g * 64 + dh * 32);
    float wg = lg[g];
    #pragma unroll
    for (int i = 0; i < 4; ++i) {
      uint4 u = vs[i];
      float2 v0 = up2(u.x), v1 = up2(u.y), v2 = up2(u.z), v3 = up2(u.w);
      oa[i*8+0] += wg*v0.x; oa[i*8+1] += wg*v0.y;
      oa[i*8+2] += wg*v1.x; oa[i*8+3] += wg*v1.y;
      oa[i*8+4] += wg*v2.x; oa[i*8+5] += wg*v2.y;
      oa[i*8+6] += wg*v3.x; oa[i*8+7] += wg*v3.y;
    }
  }
  ushortT* dst = o + (size_t)(p0 + pos) * 512 + h * 64 + dh * 32;
  #pragma unroll
  for (int i = 0; i < 4; ++i) {
    uint4 w_;
    w_.x = (unsigned)f2bf(oa[i*8+0]) | ((unsigned)f2bf(oa[i*8+1]) << 16);
    w_.y = (unsigned)f2bf(oa[i*8+2]) | ((unsigned)f2bf(oa[i*8+3]) << 16);
    w_.z = (unsigned)f2bf(oa[i*8+4]) | ((unsigned)f2bf(oa[i*8+5]) << 16);
    w_.w = (unsigned)f2bf(oa[i*8+6]) | ((unsigned)f2bf(oa[i*8+7]) << 16);
    *(uint4*)(dst + i * 8) = w_;
  }
}

// ---------------- K5: proj GEMM + residual + transposed fp32 write ---------
// grid 2048 = 512 m-tiles x 4 n-tiles; 128^2 core; per-wave fp32 transpose
// in the freed 16 KB (stride 64 floats: lane-stride-1 reads conflict-free).
__global__ __launch_bounds__(256) void gemm_proj(const ushortT* __restrict__ o,
                                                 const ushortT* __restrict__ wp,
                                                 const float* __restrict__ bias,
                                                 const float* __restrict__ x,
                                                 float* __restrict__ out) {
  __shared__ ushortT lds[8192];                 // 16 KB
  int bid = blockIdx.x;
  int wg = (bid & 7) * 256 + (bid >> 3);        // bijective (2048 % 8 == 0)
  int m0 = (wg >> 2) * 128, n0 = (wg & 3) * 128;
  float4v acc[4][4] = {};
  core128(o, wp, lds, m0, n0, acc);
  const int tid = threadIdx.x;
  const int w = tid >> 6, l = tid & 63;
  const int wm = w >> 1, wn = w & 1;
  __syncthreads();
  float* es = (float*)lds + w * 1024;           // 16 x 64 floats per wave
  int b = m0 >> 12;                             // 128-row tile within batch
  int c = n0 + wn * 64 + l;
  float bc = bias[c];
  const float* xrow = x + ((size_t)b * 512 + c) * 4096;
  float* orow = out + ((size_t)b * 512 + c) * 4096;
  int nb0 = (m0 & 4095) + wm * 64;
  #pragma unroll
  for (int fm = 0; fm < 4; ++fm) {
    #pragma unroll
    for (int fn = 0; fn < 4; ++fn)
      #pragma unroll
      for (int j = 0; j < 4; ++j)
        es[((l >> 4) * 4 + j) * 64 + fn * 16 + (l & 15)] = acc[fm][fn][j];
    int nb = nb0 + fm * 16;
    #pragma unroll
    for (int q4 = 0; q4 < 4; ++q4) {
      float4 xv = *(const float4*)(xrow + nb + q4 * 4);
      float4 ov;
      ov.x = xv.x + bc + es[(q4 * 4 + 0) * 64 + l];
      ov.y = xv.y + bc + es[(q4 * 4 + 1) * 64 + l];
      ov.z = xv.z + bc + es[(q4 * 4 + 2) * 64 + l];
      ov.w = xv.w + bc + es[(q4 * 4 + 3) * 64 + l];
      *(float4*)(orow + nb + q4 * 4) = ov;
    }
  }
}

// ---------------- launcher ----------------
extern "C" void kernel_launch(void* const* d_in, const int* in_sizes, int n_in,
                              void* d_out, int out_size, void* d_ws, size_t ws_size,
                              hipStream_t stream) {
  const float* x     = (const float*)d_in[0];
  const float* nw    = (const float*)d_in[1];
  const float* nb    = (const float*)d_in[2];
  const float* qkvw  = (const float*)d_in[3];
  const float* qkvb  = (const float*)d_in[4];
  const float* pw    = (const float*)d_in[5];
  const float* pb    = (const float*)d_in[6];
  float* out = (float*)d_out;
  char* ws = (char*)d_ws;

  const size_t OFF_WQ   = 4096;
  const size_t OFF_WP   = OFF_WQ + 1572864;
  const size_t OFF_H    = OFF_WP + 524288;
  const size_t OFF_QKV  = OFF_H + 67108864;

  float2* stats   = (float2*)ws;
  ushortT* wq_b   = (ushortT*)(ws + OFF_WQ);
  ushortT* wp_b   = (ushortT*)(ws + OFF_WP);
  ushortT* h      = (ushortT*)(ws + OFF_H);
  ushortT* qkv    = (ushortT*)(ws + OFF_QKV);

  prep<<<1536, 256, 0, stream>>>(qkvw, pw, x, wq_b, wp_b, stats);
  norm_tr<<<dim3(64, 8, 16), dim3(64, 8), 0, stream>>>(x, nw, nb, stats, h);
  gemm_qkv<<<6144, 256, 0, stream>>>(h, wq_b, qkvb, qkv);
  attn_k<<<4096, 256, 0, stream>>>(qkv, h);
  gemm_proj<<<2048, 256, 0, stream>>>(h, wp_b, pb, x, out);
}

// Round 12
// 351.506 us; speedup vs baseline: 1.0700x; 1.0700x over previous
//
#include <hip/hip_runtime.h>

// ---------------- types / helpers ----------------
typedef __attribute__((ext_vector_type(8))) short short8v;   // 8 bf16 (4 VGPR)
typedef __attribute__((ext_vector_type(4))) float float4v;   // MFMA acc
typedef unsigned short ushortT;

__device__ __forceinline__ unsigned short f2bf(float f) {
  union { float f; unsigned u; } a; a.f = f;
  unsigned r = a.u + 0x7fffu + ((a.u >> 16) & 1u);   // RNE
  return (unsigned short)(r >> 16);
}
__device__ __forceinline__ float2 up2(unsigned u) {  // packed 2xbf16 -> 2 floats
  union { unsigned u; float f; } a, b;
  a.u = u << 16; b.u = u & 0xffff0000u;
  return make_float2(a.f, b.f);
}
__device__ __forceinline__ void gl_lds16(const void* g, void* l) {
  __builtin_amdgcn_global_load_lds(
      (const __attribute__((address_space(1))) void*)g,
      (__attribute__((address_space(3))) void*)l, 16, 0, 0);
}

#define WAITV4 asm volatile("s_waitcnt vmcnt(4)" ::: "memory")
#define WAITV0 asm volatile("s_waitcnt vmcnt(0)" ::: "memory")
#define BAR()  __builtin_amdgcn_s_barrier()
#define MFMA16(d, a, b) d = __builtin_amdgcn_mfma_f32_16x16x32_bf16(a, b, d, 0, 0, 0)

// ---------------- K0: fused prep — weight converts + groupnorm stats -------
__global__ __launch_bounds__(256) void prep(const float* __restrict__ qkvw,
                                            const float* __restrict__ pw,
                                            const float* __restrict__ x,
                                            ushortT* __restrict__ wq_b,
                                            ushortT* __restrict__ wp_b,
                                            float2* __restrict__ stats) {
  int bid = blockIdx.x, tid = threadIdx.x;
  if (bid < 1024) {
    const float* src = (bid < 768) ? qkvw : pw;
    ushortT* dst     = (bid < 768) ? wq_b : wp_b;
    int base = (bid < 768) ? bid : (bid - 768);
    int i = (base * 256 + tid) * 4;
    float4 v = *(const float4*)(src + i);
    uint2 o;
    o.x = (unsigned)f2bf(v.x) | ((unsigned)f2bf(v.y) << 16);
    o.y = (unsigned)f2bf(v.z) | ((unsigned)f2bf(v.w) << 16);
    *(uint2*)(dst + i) = o;
    return;
  }
  int bg = bid - 1024;
  const float* base = x + (size_t)bg * 65536;
  float s = 0.f, s2 = 0.f;
  for (int i = tid; i < 16384; i += 256) {
    float4 v = *(const float4*)(base + (size_t)i * 4);
    s  += v.x + v.y + v.z + v.w;
    s2 += v.x * v.x + v.y * v.y + v.z * v.z + v.w * v.w;
  }
  #pragma unroll
  for (int off = 32; off > 0; off >>= 1) {
    s  += __shfl_down(s, off);
    s2 += __shfl_down(s2, off);
  }
  __shared__ float red[8];
  int w = tid >> 6, l = tid & 63;
  if (l == 0) { red[w] = s; red[w + 4] = s2; }
  __syncthreads();
  if (tid == 0) {
    float ts = red[0] + red[1] + red[2] + red[3];
    float t2 = red[4] + red[5] + red[6] + red[7];
    float mean = ts * (1.f / 65536.f);
    float var  = t2 * (1.f / 65536.f) - mean * mean;
    stats[bg] = make_float2(mean, rsqrtf(var + 1e-5f));
  }
}

// ---------------- K2: normalize + transpose -> h[b*n][c] bf16 ----------------
__global__ __launch_bounds__(512) void norm_tr(const float* __restrict__ x,
                                               const float* __restrict__ nw,
                                               const float* __restrict__ nb,
                                               const float2* __restrict__ stats,
                                               ushortT* __restrict__ h) {
  __shared__ float t[64][65];
  int n0 = blockIdx.x * 64, c0 = blockIdx.y * 64, b = blockIdx.z;
  int tx = threadIdx.x, ty = threadIdx.y;
  #pragma unroll
  for (int j = ty; j < 64; j += 8) {
    int c = c0 + j;
    float2 ms = stats[b * 32 + (c >> 4)];
    float v = x[((size_t)b * 512 + c) * 4096 + n0 + tx];
    t[j][tx] = (v - ms.x) * ms.y * nw[c] + nb[c];
  }
  __syncthreads();
  #pragma unroll
  for (int j = ty; j < 64; j += 8) {
    int n = n0 + j;
    h[((size_t)b * 4096 + n) * 512 + c0 + tx] = f2bf(t[tx][j]);
  }
}

// ================= 256x256 8-wave 8-phase GEMM core (R6, for qkv) ==========
__device__ __forceinline__ void core256b(const ushortT* __restrict__ A,
                                         const ushortT* __restrict__ Bm,
                                         ushortT* lds, int m0, int n0,
                                         float4v (&acc)[8][4]) {
  char* ldsb = (char*)lds;
  const int tid = threadIdx.x;
  const int w = tid >> 6, l = tid & 63;
  const int wm = w >> 2, wn = w & 3;

  const int P0b = tid * 16, P1b = 8192 + tid * 16;
  const int r0 = P0b >> 7, r1 = P1b >> 7;
  const int s0 = (P0b & 127) ^ ((r0 & 7) << 4);
  const int s1 = (P1b & 127) ^ ((r1 & 7) << 4);
  const size_t g0 = (size_t)r0 * 512 + (s0 >> 1);
  const size_t g1 = (size_t)r1 * 512 + (s1 >> 1);
  auto stage = [&](const ushortT* mat, int rowbase, int kt, int bufb, int region) {
    const ushortT* gsrc = mat + (size_t)rowbase * 512 + kt * 64;
    char* dbase = ldsb + bufb + region;
    gl_lds16(gsrc + g0, dbase + P0b);
    gl_lds16(gsrc + g1, dbase + P1b);
  };

  const int colb = (l >> 4) * 16;
  const int cs0 = colb ^ ((l & 7) << 4);
  const int cs1 = (64 + colb) ^ ((l & 7) << 4);
  const int arow = wm * 16384 + (l & 15) * 128;
  const int brow = 32768 + wn * 8192 + (l & 15) * 128;

  short8v Af[4][2], Bf[4][2];

  #define RDA4(bb, MH)                                                  \
    { _Pragma("unroll")                                                 \
      for (int mm = 0; mm < 4; ++mm) {                                  \
        const char* p = ldsb + (bb) + arow + ((MH)*4 + mm) * 2048;      \
        Af[mm][0] = *(const short8v*)(p + cs0);                         \
        Af[mm][1] = *(const short8v*)(p + cs1);                         \
      } }
  #define RDB2(bb, N0)                                                  \
    { _Pragma("unroll")                                                 \
      for (int nn = 0; nn < 2; ++nn) {                                  \
        const char* p = ldsb + (bb) + brow + ((N0) + nn) * 2048;        \
        Bf[(N0)+nn][0] = *(const short8v*)(p + cs0);                    \
        Bf[(N0)+nn][1] = *(const short8v*)(p + cs1);                    \
      } }
  #define CLUSTER(MH, NP)                                               \
    { __builtin_amdgcn_s_setprio(1);                                    \
      _Pragma("unroll")                                                 \
      for (int mm = 0; mm < 4; ++mm) {                                  \
        _Pragma("unroll")                                               \
        for (int nn = 0; nn < 2; ++nn) {                                \
          MFMA16(acc[(MH)*4+mm][(NP)*2+nn], Af[mm][0], Bf[(NP)*2+nn][0]); \
          MFMA16(acc[(MH)*4+mm][(NP)*2+nn], Af[mm][1], Bf[(NP)*2+nn][1]); \
        } }                                                             \
      __builtin_amdgcn_s_setprio(0); }

  auto tile = [&](int bb, int t1, int t2, bool s1g, bool s2g, int vw) {
    RDB2(bb, 0); RDA4(bb, 0);
    if (s1g) stage(A, m0 + 128, t1, bb ^ 65536, 16384);
    BAR();
    CLUSTER(0, 0);
    BAR();
    RDB2(bb, 2);
    if (s1g) stage(Bm, n0 + 128, t1, bb ^ 65536, 49152);
    BAR();
    CLUSTER(0, 1);
    BAR();
    RDA4(bb, 1);
    if (s2g) stage(Bm, n0, t2, bb, 32768);
    BAR();
    CLUSTER(1, 1);
    BAR();
    if (s2g) stage(A, m0, t2, bb, 0);
    if (vw == 4)      { WAITV4; }
    else if (vw == 0) { WAITV0; }
    BAR();
    CLUSTER(1, 0);
    BAR();
  };

  stage(A,  m0,       0, 0, 0);
  stage(A,  m0 + 128, 0, 0, 16384);
  stage(Bm, n0,       0, 0, 32768);
  stage(Bm, n0 + 128, 0, 0, 49152);
  stage(Bm, n0,       1, 65536, 32768);
  stage(A,  m0,       1, 65536, 0);
  WAITV4;
  BAR();

  #pragma unroll 1
  for (int tp = 0; tp < 3; ++tp) {
    tile(0,     2 * tp + 1, 2 * tp + 2, true, true, 4);
    tile(65536, 2 * tp + 2, 2 * tp + 3, true, true, 4);
  }
  tile(0,     7, 8, true,  false, 0);
  tile(65536, 8, 9, false, false, -1);
  #undef RDA4
  #undef RDB2
  #undef CLUSTER
}

// ================= m97-style 128x128 GEMM core (R11, for proj) =============
// 256 thr / 4 waves, BK=32, 16 KB LDS, 2-barrier K-loop. ~110 VGPR + 64 acc
// -> 2 blocks/CU: cross-block overlap hides staging + the fp32 epilogue.
__device__ __forceinline__ void core128(const ushortT* __restrict__ A,
                                        const ushortT* __restrict__ Bm,
                                        ushortT* lds, int m0, int n0,
                                        float4v (&acc)[4][4]) {
  char* ldsb = (char*)lds;
  const int tid = threadIdx.x;
  const int w = tid >> 6, l = tid & 63;
  const int wm = w >> 1, wn = w & 1;

  const int r0 = tid >> 2, r1 = (256 + tid) >> 2;
  const int s0 = (tid & 3) ^ ((r0 >> 1) & 3);
  const int s1 = (tid & 3) ^ ((r1 >> 1) & 3);
  const size_t gA0 = (size_t)r0 * 512 + s0 * 8;
  const size_t gA1 = (size_t)r1 * 512 + s1 * 8;
  const int d0 = tid * 16, d1 = (256 + tid) * 16;

  const int cs = ((l >> 4) ^ (((l & 15) >> 1) & 3)) * 16;
  const int ab = wm * 4096 + (l & 15) * 64 + cs;
  const int bb = 8192 + wn * 4096 + (l & 15) * 64 + cs;

  const ushortT* pa = A + (size_t)m0 * 512;
  const ushortT* pb = Bm + (size_t)n0 * 512;

  #pragma unroll 1
  for (int kt = 0; kt < 16; ++kt) {
    if (kt) __syncthreads();
    gl_lds16(pa + gA0 + kt * 32, ldsb + d0);
    gl_lds16(pa + gA1 + kt * 32, ldsb + d1);
    gl_lds16(pb + gA0 + kt * 32, ldsb + 8192 + d0);
    gl_lds16(pb + gA1 + kt * 32, ldsb + 8192 + d1);
    __syncthreads();
    short8v Af[4], Bf[4];
    #pragma unroll
    for (int i = 0; i < 4; ++i) {
      Af[i] = *(const short8v*)(ldsb + ab + i * 1024);
      Bf[i] = *(const short8v*)(ldsb + bb + i * 1024);
    }
    #pragma unroll
    for (int mi = 0; mi < 4; ++mi)
      #pragma unroll
      for (int ni = 0; ni < 4; ++ni)
        MFMA16(acc[mi][ni], Af[mi], Bf[ni]);
  }
}

// ---------------- K3: qkv GEMM (65536 x 1536 x 512) -> bf16 (256^2 core) ---
__global__ __launch_bounds__(512, 2) void gemm_qkv(const ushortT* __restrict__ h,
                                                   const ushortT* __restrict__ wq,
                                                   const float* __restrict__ bias,
                                                   ushortT* __restrict__ outq) {
  __shared__ ushortT lds[65536];   // 128 KB
  int bid = blockIdx.x;
  int wg = (bid & 7) * 192 + (bid >> 3);         // bijective XCD swizzle
  int m0 = (wg / 6) * 256, n0 = (wg % 6) * 256;  // N fastest -> A reused in L2
  float4v acc[8][4] = {};
  core256b(h, wq, lds, m0, n0, acc);
  const int tid = threadIdx.x;
  const int w = tid >> 6, l = tid & 63;
  const int wm = w >> 2, wn = w & 3;
  __syncthreads();
  ushortT* es = lds + w * 1280;              // 16 x 72 shorts per wave
  float bb[4];
  #pragma unroll
  for (int fn = 0; fn < 4; ++fn) bb[fn] = bias[n0 + wn * 64 + fn * 16 + (l & 15)];
  int r = l >> 2, g = l & 3;
  #pragma unroll
  for (int fm = 0; fm < 8; ++fm) {
    #pragma unroll
    for (int fn = 0; fn < 4; ++fn)
      #pragma unroll
      for (int j = 0; j < 4; ++j)
        es[((l >> 4) * 4 + j) * 72 + fn * 16 + (l & 15)] = f2bf(acc[fm][fn][j] + bb[fn]);
    uint4 v0 = *(const uint4*)(es + r * 72 + g * 16);
    uint4 v1 = *(const uint4*)(es + r * 72 + g * 16 + 8);
    size_t mrow = (size_t)m0 + wm * 128 + fm * 16 + r;
    uint4* dst = (uint4*)(outq + mrow * 1536 + n0 + wn * 64 + g * 16);
    dst[0] = v0; dst[1] = v1;
  }
}

// ---------------- K4: attention, LDS-staged & fully coalesced (R10) --------
__global__ __launch_bounds__(256) void attn_k(const ushortT* __restrict__ qkv,
                                              ushortT* __restrict__ o) {
  __shared__ ushortT kv[16 * 1544];            // 49408 B
  const int tid = threadIdx.x;
  const int p0 = blockIdx.x * 16;

  #pragma unroll
  for (int j = 0; j < 12; ++j) {
    int c = j * 256 + tid;
    int row = c / 192, col = c % 192;          // row wave-uniform (64 | 192)
    gl_lds16(qkv + (size_t)(p0 + row) * 1536 + col * 8,
             (char*)kv + row * 3088 + col * 16);
  }
  __syncthreads();

  const int pos = tid >> 4, h = (tid >> 1) & 7, dh = tid & 1;
  const ushortT* rowp = kv + pos * 1544;

  unsigned qv[16];
  {
    const uint4* qs = (const uint4*)(rowp + h * 64 + dh * 32);
    #pragma unroll
    for (int i = 0; i < 4; ++i) {
      uint4 u = qs[i];
      qv[i*4+0] = u.x; qv[i*4+1] = u.y; qv[i*4+2] = u.z; qv[i*4+3] = u.w;
    }
  }
  float lg[8];
  #pragma unroll
  for (int g = 0; g < 8; ++g) {
    const uint4* ks = (const uint4*)(rowp + 512 + g * 64 + dh * 32);
    float s = 0.f;
    #pragma unroll
    for (int i = 0; i < 4; ++i) {
      uint4 u = ks[i];
      float2 k0 = up2(u.x), k1 = up2(u.y), k2 = up2(u.z), k3 = up2(u.w);
      float2 q0 = up2(qv[i*4+0]), q1 = up2(qv[i*4+1]);
      float2 q2 = up2(qv[i*4+2]), q3 = up2(qv[i*4+3]);
      s += q0.x*k0.x + q0.y*k0.y + q1.x*k1.x + q1.y*k1.y
         + q2.x*k2.x + q2.y*k2.y + q3.x*k3.x + q3.y*k3.y;
    }
    s += __shfl_xor(s, 1);                     // combine the two d-halves
    lg[g] = s * 0.125f;
  }
  float mx = lg[0];
  #pragma unroll
  for (int g = 1; g < 8; ++g) mx = fmaxf(mx, lg[g]);
  float ssum = 0.f;
  #pragma unroll
  for (int g = 0; g < 8; ++g) { lg[g] = __expf(lg[g] - mx); ssum += lg[g]; }
  float inv = 1.f / ssum;
  #pragma unroll
  for (int g = 0; g < 8; ++g) lg[g] *= inv;

  float oa[32];
  #pragma unroll
  for (int i = 0; i < 32; ++i) oa[i] = 0.f;
  #pragma unroll
  for (int g = 0; g < 8; ++g) {
    const uint4* vs = (const uint4*)(rowp + 1024 + g * 64 + dh * 32);
    float wg = lg[g];
    #pragma unroll
    for (int i = 0; i < 4; ++i) {
      uint4 u = vs[i];
      float2 v0 = up2(u.x), v1 = up2(u.y), v2 = up2(u.z), v3 = up2(u.w);
      oa[i*8+0] += wg*v0.x; oa[i*8+1] += wg*v0.y;
      oa[i*8+2] += wg*v1.x; oa[i*8+3] += wg*v1.y;
      oa[i*8+4] += wg*v2.x; oa[i*8+5] += wg*v2.y;
      oa[i*8+6] += wg*v3.x; oa[i*8+7] += wg*v3.y;
    }
  }
  ushortT* dst = o + (size_t)(p0 + pos) * 512 + h * 64 + dh * 32;
  #pragma unroll
  for (int i = 0; i < 4; ++i) {
    uint4 w_;
    w_.x = (unsigned)f2bf(oa[i*8+0]) | ((unsigned)f2bf(oa[i*8+1]) << 16);
    w_.y = (unsigned)f2bf(oa[i*8+2]) | ((unsigned)f2bf(oa[i*8+3]) << 16);
    w_.z = (unsigned)f2bf(oa[i*8+4]) | ((unsigned)f2bf(oa[i*8+5]) << 16);
    w_.w = (unsigned)f2bf(oa[i*8+6]) | ((unsigned)f2bf(oa[i*8+7]) << 16);
    *(uint4*)(dst + i * 8) = w_;
  }
}

// ---------------- K5: proj GEMM + residual + transposed fp32 write (128^2) -
__global__ __launch_bounds__(256) void gemm_proj(const ushortT* __restrict__ o,
                                                 const ushortT* __restrict__ wp,
                                                 const float* __restrict__ bias,
                                                 const float* __restrict__ x,
                                                 float* __restrict__ out) {
  __shared__ ushortT lds[8192];                 // 16 KB
  int bid = blockIdx.x;
  int wg = (bid & 7) * 256 + (bid >> 3);        // bijective (2048 % 8 == 0)
  int m0 = (wg >> 2) * 128, n0 = (wg & 3) * 128;
  float4v acc[4][4] = {};
  core128(o, wp, lds, m0, n0, acc);
  const int tid = threadIdx.x;
  const int w = tid >> 6, l = tid & 63;
  const int wm = w >> 1, wn = w & 1;
  __syncthreads();
  float* es = (float*)lds + w * 1024;           // 16 x 64 floats per wave
  int b = m0 >> 12;
  int c = n0 + wn * 64 + l;
  float bc = bias[c];
  const float* xrow = x + ((size_t)b * 512 + c) * 4096;
  float* orow = out + ((size_t)b * 512 + c) * 4096;
  int nb0 = (m0 & 4095) + wm * 64;
  #pragma unroll
  for (int fm = 0; fm < 4; ++fm) {
    #pragma unroll
    for (int fn = 0; fn < 4; ++fn)
      #pragma unroll
      for (int j = 0; j < 4; ++j)
        es[((l >> 4) * 4 + j) * 64 + fn * 16 + (l & 15)] = acc[fm][fn][j];
    int nb = nb0 + fm * 16;
    #pragma unroll
    for (int q4 = 0; q4 < 4; ++q4) {
      float4 xv = *(const float4*)(xrow + nb + q4 * 4);
      float4 ov;
      ov.x = xv.x + bc + es[(q4 * 4 + 0) * 64 + l];
      ov.y = xv.y + bc + es[(q4 * 4 + 1) * 64 + l];
      ov.z = xv.z + bc + es[(q4 * 4 + 2) * 64 + l];
      ov.w = xv.w + bc + es[(q4 * 4 + 3) * 64 + l];
      *(float4*)(orow + nb + q4 * 4) = ov;
    }
  }
}

// ---------------- launcher ----------------
extern "C" void kernel_launch(void* const* d_in, const int* in_sizes, int n_in,
                              void* d_out, int out_size, void* d_ws, size_t ws_size,
                              hipStream_t stream) {
  const float* x     = (const float*)d_in[0];
  const float* nw    = (const float*)d_in[1];
  const float* nb    = (const float*)d_in[2];
  const float* qkvw  = (const float*)d_in[3];
  const float* qkvb  = (const float*)d_in[4];
  const float* pw    = (const float*)d_in[5];
  const float* pb    = (const float*)d_in[6];
  float* out = (float*)d_out;
  char* ws = (char*)d_ws;

  const size_t OFF_WQ   = 4096;
  const size_t OFF_WP   = OFF_WQ + 1572864;
  const size_t OFF_H    = OFF_WP + 524288;
  const size_t OFF_QKV  = OFF_H + 67108864;

  float2* stats   = (float2*)ws;
  ushortT* wq_b   = (ushortT*)(ws + OFF_WQ);
  ushortT* wp_b   = (ushortT*)(ws + OFF_WP);
  ushortT* h      = (ushortT*)(ws + OFF_H);
  ushortT* qkv    = (ushortT*)(ws + OFF_QKV);

  prep<<<1536, 256, 0, stream>>>(qkvw, pw, x, wq_b, wp_b, stats);
  norm_tr<<<dim3(64, 8, 16), dim3(64, 8), 0, stream>>>(x, nw, nb, stats, h);
  gemm_qkv<<<1536, 512, 0, stream>>>(h, wq_b, qkvb, qkv);
  attn_k<<<4096, 256, 0, stream>>>(qkv, h);
  gemm_proj<<<2048, 256, 0, stream>>>(h, wp_b, pb, x, out);
}